// Round 1
// baseline (474.739 us; speedup 1.0000x reference)
//
#include <hip/hip_runtime.h>
#include <math.h>

// Problem constants (from reference):
#define NROWS 1000000
#define NF    64      // N_FIXED
#define BB    5000    // B
#define LLg   10      // L
#define TTg   25      // T
#define KKg   8       // K

// ws layout (in floats):
//   [0,   80)   rho   = tanh(raw_rho)          (L,K)
//   [80, 160)   d     = diag(chol(Sigma[k]))   (L,K)
//   [160, 672)  betaT[k][f] = beta[f][k]       (K,NF)
//   [1024, 1024+T*B*L*K)  u table (T,B,L,K)    40 MB
#define WS_RHO   0
#define WS_D     80
#define WS_BETAT 160
#define WS_U     1024

// ---------------------------------------------------------------------------
// Prep: rho = tanh(raw_rho); d = diag of per-k Cholesky(Sigma); betaT.
// Tiny single-block kernel.
// ---------------------------------------------------------------------------
__global__ void prep_kernel(const float* __restrict__ beta,
                            const float* __restrict__ raw_rho,
                            const float* __restrict__ Sigma,
                            float* __restrict__ ws) {
    const int tid = threadIdx.x;
    for (int i = tid; i < LLg * KKg; i += blockDim.x)
        ws[WS_RHO + i] = tanhf(raw_rho[i]);
    for (int i = tid; i < KKg * NF; i += blockDim.x) {
        const int k = i / NF, f = i % NF;
        ws[WS_BETAT + i] = beta[f * KKg + k];
    }
    if (tid < KKg) {
        const int k = tid;
        float Lf[LLg][LLg];
        const float* S = Sigma + k * LLg * LLg;
        for (int i = 0; i < LLg; ++i) {
            for (int j = 0; j <= i; ++j) {
                float s = S[i * LLg + j];
                for (int m = 0; m < j; ++m) s -= Lf[i][m] * Lf[j][m];
                if (i == j) Lf[i][i] = sqrtf(s);
                else        Lf[i][j] = s / Lf[j][j];
            }
        }
        for (int l = 0; l < LLg; ++l)
            ws[WS_D + l * KKg + k] = Lf[l][l];
    }
}

// ---------------------------------------------------------------------------
// u table: u[t,b,l,k] AR(1) recurrence. One thread per (b,l,k) = 400k threads.
// eps layout (B,L,T,K): contiguous (T,K) block per (b,l). Stores coalesced.
// ---------------------------------------------------------------------------
__global__ __launch_bounds__(256) void u_kernel(const float* __restrict__ eps,
                                                const float* __restrict__ ws,
                                                float* __restrict__ u) {
    const int tid = blockIdx.x * blockDim.x + threadIdx.x;
    if (tid >= BB * LLg * KKg) return;
    const int k = tid % KKg;
    const int l = (tid / KKg) % LLg;
    const int b = tid / (KKg * LLg);
    const float rho = ws[WS_RHO + l * KKg + k];
    const float dv  = ws[WS_D   + l * KKg + k];
    const float* ep = eps + ((size_t)(b * LLg + l) * TTg) * KKg + k;
    float* up = u + (size_t)(b * LLg + l) * KKg + k;   // t=0 slot
    const size_t ustride = (size_t)BB * LLg * KKg;     // stride in t
    float uv = ep[0];
    up[0] = uv;
    for (int t = 1; t < TTg; ++t) {
        uv = rho * uv + dv * ep[(size_t)t * KKg];
        up[(size_t)t * ustride] = uv;
    }
}

// ---------------------------------------------------------------------------
// Main: out[row,k] = dot(X[row,:], beta[:,k]) + u[sea,bat,lea,k]
// k-split: lane c = gt&7 owns k=c for its row group. beta column held in
// 64 VGPRs, hoisted out of the grid-stride row loop. Output + u-gather are
// 32 B-contiguous per row group (coalesced). X row reads are 8-way
// same-address broadcast within the group (one fetch per line).
// ---------------------------------------------------------------------------
template <bool USE_TABLE>
__global__ __launch_bounds__(256) void main_kernel(
    const float* __restrict__ X,
    const int*   __restrict__ bat,
    const int*   __restrict__ lea,
    const int*   __restrict__ sea,
    const float* __restrict__ ws,
    const float* __restrict__ u_table,
    const float* __restrict__ eps,
    float*       __restrict__ out)
{
    const int gt = blockIdx.x * blockDim.x + threadIdx.x;
    const int c  = gt & 7;           // which k this lane owns
    const int g0 = gt >> 3;          // row-group id
    const int ngroups = (gridDim.x * blockDim.x) >> 3;

    // beta column c -> registers (16 coalesced float4, once per thread)
    float bc[NF];
    const float4* bt4 = (const float4*)(ws + WS_BETAT + c * NF);
#pragma unroll
    for (int j = 0; j < NF / 4; ++j) {
        const float4 v = bt4[j];
        bc[4 * j + 0] = v.x; bc[4 * j + 1] = v.y;
        bc[4 * j + 2] = v.z; bc[4 * j + 3] = v.w;
    }

    for (int row = g0; row < NROWS; row += ngroups) {
        const int b = bat[row];
        const int l = lea[row];
        const int t = sea[row];

        float uv;
        if (USE_TABLE) {
            uv = u_table[(((size_t)t * BB + b) * LLg + l) * KKg + c];
        } else {
            const float rho = ws[WS_RHO + l * KKg + c];
            const float dv  = ws[WS_D   + l * KKg + c];
            const float* ep = eps + ((size_t)(b * LLg + l) * TTg) * KKg + c;
            uv = ep[0];
            for (int tt = 1; tt <= t; ++tt)
                uv = rho * uv + dv * ep[(size_t)tt * KKg];
        }

        float acc = 0.f;
        const float4* x4 = (const float4*)(X + (size_t)row * NF);
#pragma unroll
        for (int j = 0; j < NF / 4; ++j) {
            const float4 v = x4[j];
            acc += v.x * bc[4 * j + 0] + v.y * bc[4 * j + 1]
                 + v.z * bc[4 * j + 2] + v.w * bc[4 * j + 3];
        }

        out[(size_t)row * KKg + c] = acc + uv;
    }
}

extern "C" void kernel_launch(void* const* d_in, const int* in_sizes, int n_in,
                              void* d_out, int out_size, void* d_ws, size_t ws_size,
                              hipStream_t stream) {
    const float* X       = (const float*)d_in[0];
    const int*   bat     = (const int*)  d_in[1];
    const int*   lea     = (const int*)  d_in[2];
    const int*   sea     = (const int*)  d_in[3];
    const float* beta    = (const float*)d_in[4];
    const float* raw_rho = (const float*)d_in[5];
    const float* Sigma   = (const float*)d_in[6];
    const float* eps     = (const float*)d_in[7];
    float* out = (float*)d_out;
    float* ws  = (float*)d_ws;
    float* u   = ws + WS_U;

    const size_t need_bytes = ((size_t)WS_U + (size_t)TTg * BB * LLg * KKg) * sizeof(float);
    const bool use_table = ws_size >= need_bytes;   // constant per harness -> graph-safe

    prep_kernel<<<1, 128, 0, stream>>>(beta, raw_rho, Sigma, ws);

    if (use_table) {
        u_kernel<<<(BB * LLg * KKg + 255) / 256, 256, 0, stream>>>(eps, ws, u);
        main_kernel<true><<<4096, 256, 0, stream>>>(X, bat, lea, sea, ws, u, eps, out);
    } else {
        main_kernel<false><<<4096, 256, 0, stream>>>(X, bat, lea, sea, ws, u, eps, out);
    }
}